// Round 5
// baseline (242.387 us; speedup 1.0000x reference)
//
#include <hip/hip_runtime.h>
#include <stdint.h>

typedef __attribute__((ext_vector_type(8))) short short8;
typedef __attribute__((ext_vector_type(8))) unsigned short ushort8;
typedef __attribute__((ext_vector_type(4))) unsigned short ushort4v;
typedef __attribute__((ext_vector_type(4))) float float4v;

#define D_MODEL 1024
#define NHEAD 16
#define DIM_HEAD 64
#define BATCH 2
#define SEQ 2048
#define BH (BATCH*NHEAD)
#define MROWS (BATCH*SEQ)   // 4096
#define MK ((size_t)MROWS * D_MODEL)   // 4194304 elems per activation tensor

__device__ __forceinline__ unsigned short f2bf(float f) {
  union { float f; unsigned u; } v; v.f = f;
  unsigned r = v.u + 0x7fffu + ((v.u >> 16) & 1u);   // RNE
  return (unsigned short)(r >> 16);
}
__device__ __forceinline__ unsigned short f2bf_fast(float f) {
  union { float f; unsigned u; } v; v.f = f;
  return (unsigned short)((v.u + 0x8000u) >> 16);
}

// async global->LDS, 16B per lane; lds base must be wave-uniform
__device__ __forceinline__ void gld16(const unsigned short* g, unsigned short* l) {
  __builtin_amdgcn_global_load_lds(
      (const __attribute__((address_space(1))) unsigned int*)g,
      (__attribute__((address_space(3))) unsigned int*)l, 16, 0, 0);
}

// ---- weight transpose+cast (all 4 weights in one launch, z picks) ----------
// WT[z][n][k] = bf16(W[z][k][n] * scale[z])
__global__ __launch_bounds__(256) void wtrans_kernel(const float* __restrict__ W0,
    const float* __restrict__ W1, const float* __restrict__ W2,
    const float* __restrict__ W3, unsigned short* __restrict__ WT) {
  __shared__ float tile[32][33];
  const int z = blockIdx.z;
  const float* W = (z == 0) ? W0 : (z == 1) ? W1 : (z == 2) ? W2 : W3;
  const float scale = (z == 0) ? 0.125f : 1.0f;   // fold SCALE into Wq
  unsigned short* dst = WT + ((size_t)z << 20);
  int bn = blockIdx.x * 32;
  int bk = blockIdx.y * 32;
  int tx = threadIdx.x & 31, ty = threadIdx.x >> 5;
#pragma unroll
  for (int i = 0; i < 4; i++)
    tile[ty + i*8][tx] = W[(size_t)(bk + ty + i*8) * D_MODEL + bn + tx];
  __syncthreads();
#pragma unroll
  for (int i = 0; i < 4; i++)
    dst[(size_t)(bn + ty + i*8) * D_MODEL + bk + tx] = f2bf(tile[tx][ty + i*8] * scale);
}

// ---- cast q/k/v fp32 -> bf16, z picks tensor -------------------------------
__global__ __launch_bounds__(256) void cast_kernel(const float* __restrict__ q,
    const float* __restrict__ k, const float* __restrict__ v,
    unsigned short* __restrict__ out) {
  const float* src = (blockIdx.y == 0) ? q : (blockIdx.y == 1) ? k : v;
  unsigned short* dst = out + (size_t)blockIdx.y * MK;
  size_t idx = ((size_t)blockIdx.x * 256 + threadIdx.x) * 8;
  float4v a = *(const float4v*)(src + idx);
  float4v b = *(const float4v*)(src + idx + 4);
  ushort8 o;
  o[0] = f2bf(a[0]); o[1] = f2bf(a[1]); o[2] = f2bf(a[2]); o[3] = f2bf(a[3]);
  o[4] = f2bf(b[0]); o[5] = f2bf(b[1]); o[6] = f2bf(b[2]); o[7] = f2bf(b[3]);
  *(ushort8*)(dst + idx) = o;
}

// ---- V transpose: Vb [b,n,h,d] -> VT_perm [b,h,d, blk*64 + e] --------------
// Bit-swap perm within each 64-block: row e holds original k(e) =
// 32*(e>>5) + 16*((e>>2)&1) + 4*((e>>3)&3) + (e&3).
// This matches the in-lane layout of exp(S^T) from the swapped QK^T so P
// feeds PV's A-operand directly with ZERO LDS traffic (PV contracts over e).
__global__ __launch_bounds__(256) void vtrans_kernel(const unsigned short* __restrict__ Vb,
                                                     unsigned short* __restrict__ VT) {
  __shared__ unsigned short tile[64][72];
  const int bh = blockIdx.x;
  const int b = bh >> 4, h = bh & 15;
  const int n0 = blockIdx.y * 64;
  const int t = threadIdx.x;
#pragma unroll
  for (int p = 0; p < 2; p++) {
    int g = p*256 + t; int row = g >> 3, c = g & 7;
    *(ushort8*)&tile[row][c*8] =
      *(const ushort8*)(Vb + ((size_t)((b*SEQ + n0 + row)*NHEAD + h))*DIM_HEAD + c*8);
  }
  __syncthreads();
  int d = t >> 2, base = (t & 3) * 16;
  ushort8 o0, o1;
#pragma unroll
  for (int m = 0; m < 8; m++) {
    int e0 = base + m, e1 = base + 8 + m;
    int k0_ = 32*(e0>>5) + 16*((e0>>2)&1) + 4*((e0>>3)&3) + (e0&3);
    int k1_ = 32*(e1>>5) + 16*((e1>>2)&1) + 4*((e1>>3)&3) + (e1&3);
    o0[m] = tile[k0_][d];
    o1[m] = tile[k1_][d];
  }
  unsigned short* dst = VT + ((size_t)(bh*DIM_HEAD + d))*SEQ + n0 + base;
  *(ushort8*)dst = o0;
  *(ushort8*)(dst + 8) = o1;
}

// ---- fused QKV projection: z in {0,1,2}; m97-style (unpadded LDS + gld16) --
// Y[z](bf16)[4096,1024] = Xbf[z] @ W[z],  WT[z] is B^T [N,K]
__global__ __launch_bounds__(256, 3) void proj_kernel(const unsigned short* __restrict__ Xbf,
    const unsigned short* __restrict__ WT0, unsigned short* __restrict__ Y0) {
  __shared__ unsigned short Al[128*64];   // 16 KB, row stride 64 (unpadded)
  __shared__ unsigned short Bl[128*64];   // 16 KB
  const int z = blockIdx.z;
  const unsigned short* A  = Xbf + (size_t)z * MK;
  const unsigned short* BT = WT0 + ((size_t)z << 20);
  unsigned short* Y = Y0 + (size_t)z * MK;
  const int m0 = blockIdx.x * 128, n0 = blockIdx.y * 128;
  const int t = threadIdx.x;
  const int lane = t & 63, w = t >> 6, quad = lane >> 4, lid = lane & 15;
  const int wm = w & 1, wn = w >> 1;
  const int r8 = lane >> 3, c8 = (lane & 7) * 8;

  float4v acc[4][4];
#pragma unroll
  for (int i = 0; i < 4; i++)
#pragma unroll
    for (int j = 0; j < 4; j++) acc[i][j] = (float4v)0.0f;

  for (int k0 = 0; k0 < D_MODEL; k0 += 64) {
#pragma unroll
    for (int p = 0; p < 4; p++) {
      int seg = w*4 + p;   // 16 segs x 8 rows x 1KB
      gld16(A  + (size_t)(m0 + seg*8 + r8) * D_MODEL + k0 + c8, &Al[seg*8*64]);
      gld16(BT + (size_t)(n0 + seg*8 + r8) * D_MODEL + k0 + c8, &Bl[seg*8*64]);
    }
    __syncthreads();
#pragma unroll
    for (int kst = 0; kst < 2; kst++) {
      short8 af[4], bfr[4];
#pragma unroll
      for (int i = 0; i < 4; i++)
        af[i] = *(const short8*)&Al[(wm*64 + i*16 + lid)*64 + kst*32 + quad*8];
#pragma unroll
      for (int j = 0; j < 4; j++)
        bfr[j] = *(const short8*)&Bl[(wn*64 + j*16 + lid)*64 + kst*32 + quad*8];
#pragma unroll
      for (int i = 0; i < 4; i++)
#pragma unroll
        for (int j = 0; j < 4; j++)
          acc[i][j] = __builtin_amdgcn_mfma_f32_16x16x32_bf16(af[i], bfr[j], acc[i][j], 0, 0, 0);
    }
    __syncthreads();
  }
#pragma unroll
  for (int i = 0; i < 4; i++)
#pragma unroll
    for (int j = 0; j < 4; j++)
#pragma unroll
      for (int r = 0; r < 4; r++) {
        int row = m0 + wm*64 + i*16 + quad*4 + r;
        int col = n0 + wn*64 + j*16 + lid;
        Y[(size_t)row * D_MODEL + col] = f2bf_fast(acc[i][j][r]);
      }
}

// ---- output projection: out(fp32)[4096,1024] = A(bf16) @ Wo + bo -----------
// BM=64, BN=128 -> 512 blocks (2/CU)
__global__ __launch_bounds__(256, 3) void outproj_kernel(const unsigned short* __restrict__ A,
    const unsigned short* __restrict__ WT, const float* __restrict__ bias,
    float* __restrict__ out) {
  __shared__ unsigned short Al[64*64];    //  8 KB
  __shared__ unsigned short Bl[128*64];   // 16 KB
  const int m0 = blockIdx.x * 64, n0 = blockIdx.y * 128;
  const int t = threadIdx.x;
  const int lane = t & 63, w = t >> 6, quad = lane >> 4, lid = lane & 15;
  const int wm = w & 1, wn = w >> 1;
  const int r8 = lane >> 3, c8 = (lane & 7) * 8;

  float4v acc[2][4];
#pragma unroll
  for (int i = 0; i < 2; i++)
#pragma unroll
    for (int j = 0; j < 4; j++) acc[i][j] = (float4v)0.0f;

  for (int k0 = 0; k0 < D_MODEL; k0 += 64) {
#pragma unroll
    for (int p = 0; p < 2; p++) {
      int seg = w*2 + p;   // 8 segs for A
      gld16(A + (size_t)(m0 + seg*8 + r8) * D_MODEL + k0 + c8, &Al[seg*8*64]);
    }
#pragma unroll
    for (int p = 0; p < 4; p++) {
      int seg = w*4 + p;   // 16 segs for B
      gld16(WT + (size_t)(n0 + seg*8 + r8) * D_MODEL + k0 + c8, &Bl[seg*8*64]);
    }
    __syncthreads();
#pragma unroll
    for (int kst = 0; kst < 2; kst++) {
      short8 af[2], bfr[4];
#pragma unroll
      for (int i = 0; i < 2; i++)
        af[i] = *(const short8*)&Al[(wm*32 + i*16 + lid)*64 + kst*32 + quad*8];
#pragma unroll
      for (int j = 0; j < 4; j++)
        bfr[j] = *(const short8*)&Bl[(wn*64 + j*16 + lid)*64 + kst*32 + quad*8];
#pragma unroll
      for (int i = 0; i < 2; i++)
#pragma unroll
        for (int j = 0; j < 4; j++)
          acc[i][j] = __builtin_amdgcn_mfma_f32_16x16x32_bf16(af[i], bfr[j], acc[i][j], 0, 0, 0);
    }
    __syncthreads();
  }
#pragma unroll
  for (int i = 0; i < 2; i++)
#pragma unroll
    for (int j = 0; j < 4; j++)
#pragma unroll
      for (int r = 0; r < 4; r++) {
        int row = m0 + wm*32 + i*16 + quad*4 + r;
        int col = n0 + wn*64 + j*16 + lid;
        out[(size_t)row * D_MODEL + col] = acc[i][j][r] + bias[col];
      }
}

// ---- flash attention v5: r3 geometry (4 waves x 32q, QB=128, 2 blk/CU) with
// K fragments DIRECT global->reg (L1-served; lanes with equal lid across quads
// cover one 64B line -> sector-coalesced), prefetched one iter ahead (A/B).
// V stays in LDS (needs the bit-swap perm layout). P stays in registers.
// This offloads ~half the LDS-port traffic onto the otherwise-idle L1 path.
#define QB 128
#define KB 64
#define FSTR 72
#define NT (SEQ/KB)   // 32

__global__ __launch_bounds__(256, 2) void flash_kernel(const unsigned short* __restrict__ Q,
    const unsigned short* __restrict__ K, const unsigned short* __restrict__ VT,
    unsigned short* __restrict__ O) {
  __shared__ unsigned short Vt[2][DIM_HEAD][FSTR];  // 18 KB

  const int bh = blockIdx.x;
  const int b = bh >> 4, h = bh & 15;
  const int q0 = blockIdx.y * QB;
  const int t = threadIdx.x;
  const int lane = t & 63, w = t >> 6, quad = lane >> 4, lid = lane & 15;
  const int prow = t >> 3, pc = (t & 7) * 8;   // V staging: 32 rows x 8 chunks; p adds 32

  const unsigned short* Kbase = K + ((size_t)(b*SEQ)*NHEAD + h)*DIM_HEAD;
  const unsigned short* Vbase = VT + (size_t)bh*DIM_HEAD*SEQ;

  // Q direct to regs: wave w owns q-rows q0 + w*32 .. +31 (2 st tiles of 16)
  short8 qf[2][2];
#pragma unroll
  for (int st = 0; st < 2; st++)
#pragma unroll
    for (int kst = 0; kst < 2; kst++)
      qf[st][kst] = *(const short8*)(Q +
          ((size_t)((b*SEQ + q0 + w*32 + st*16 + lid)*NHEAD + h))*DIM_HEAD + kst*32 + quad*8);

  float4v o[2][4];
#pragma unroll
  for (int st = 0; st < 2; st++)
#pragma unroll
    for (int i = 0; i < 4; i++) o[st][i] = (float4v)0.0f;
  float ps[2] = {0.0f, 0.0f};

  ushort8 vr[2];
  auto LOADV = [&](int kb) {
#pragma unroll
    for (int p = 0; p < 2; p++)
      vr[p] = *(const ushort8*)(Vbase + (size_t)(p*32 + prow) * SEQ + kb + pc);
  };
  auto COMMITV = [&](int bi) {
#pragma unroll
    for (int p = 0; p < 2; p++)
      *(ushort8*)&Vt[bi][p*32 + prow][pc] = vr[p];
  };
  auto LOADK = [&](int kb, short8 (&kf)[2][4]) {
#pragma unroll
    for (int kst = 0; kst < 2; kst++)
#pragma unroll
      for (int n = 0; n < 4; n++)
        kf[kst][n] = *(const short8*)(Kbase +
            (size_t)(kb + n*16 + lid) * D_MODEL + kst*32 + quad*8);
  };
  auto STEP = [&](int bi, short8 (&kf)[2][4]) {
    float4v s[2][4];
#pragma unroll
    for (int st = 0; st < 2; st++)
#pragma unroll
      for (int n = 0; n < 4; n++) s[st][n] = (float4v)0.0f;
    __builtin_amdgcn_s_setprio(1);
#pragma unroll
    for (int kst = 0; kst < 2; kst++)
#pragma unroll
      for (int n = 0; n < 4; n++) {
        s[0][n] = __builtin_amdgcn_mfma_f32_16x16x32_bf16(kf[kst][n], qf[0][kst], s[0][n], 0, 0, 0);
        s[1][n] = __builtin_amdgcn_mfma_f32_16x16x32_bf16(kf[kst][n], qf[1][kst], s[1][n], 0, 0, 0);
      }
    __builtin_amdgcn_s_setprio(0);
    // lane (quad,lid) holds S[q = st*16+lid][k = n*16 + quad*4 + r].
    // exp + in-register pack into PV A-frag slot j = 4*(n&1)+r of half n>>1
    // (effective k-order e = 32*(n>>1) + 8*quad + j matches VT's bit-swap perm).
    short8 pf0[2], pf1[2];
#pragma unroll
    for (int n = 0; n < 4; n++)
#pragma unroll
      for (int r = 0; r < 4; r++) {
        float p0 = __expf(s[0][n][r]);
        float p1 = __expf(s[1][n][r]);
        ps[0] += p0; ps[1] += p1;
        pf0[n >> 1][4*(n & 1) + r] = (short)f2bf_fast(p0);
        pf1[n >> 1][4*(n & 1) + r] = (short)f2bf_fast(p1);
      }
    __builtin_amdgcn_s_setprio(1);
#pragma unroll
    for (int kst = 0; kst < 2; kst++)
#pragma unroll
      for (int i = 0; i < 4; i++) {
        short8 vf = *(const short8*)&Vt[bi][i*16 + lid][kst*32 + quad*8];
        o[0][i] = __builtin_amdgcn_mfma_f32_16x16x32_bf16(pf0[kst], vf, o[0][i], 0, 0, 0);
        o[1][i] = __builtin_amdgcn_mfma_f32_16x16x32_bf16(pf1[kst], vf, o[1][i], 0, 0, 0);
      }
    __builtin_amdgcn_s_setprio(0);
  };

  short8 kfA[2][4], kfB[2][4];
  LOADV(0);
  COMMITV(0);
  LOADK(0, kfA);
  __syncthreads();

  for (int it = 0; it < NT; it += 2) {
    // even iter: compute buf0 with kfA; prefetch tile it+1 (V regs + kfB)
    if (it + 1 < NT) { LOADV((it + 1)*KB); LOADK((it + 1)*KB, kfB); }
    STEP(0, kfA);
    if (it + 1 < NT) COMMITV(1);
    __syncthreads();
    // odd iter: compute buf1 with kfB; prefetch tile it+2 (V regs + kfA)
    if (it + 2 < NT) { LOADV((it + 2)*KB); LOADK((it + 2)*KB, kfA); }
    if (it + 1 < NT) STEP(1, kfB);
    if (it + 2 < NT) COMMITV(0);
    __syncthreads();
  }

  // softmax denominators: lane holds partial sum for q = st*16+lid (its quad's
  // k-slice); reduce across quads, then fetch denom for output rows quad*4+r.
  float dr[2][4];
#pragma unroll
  for (int st = 0; st < 2; st++) {
    float v = ps[st];
    v += __shfl_xor(v, 16);
    v += __shfl_xor(v, 32);
    v = 1.0f / v;
#pragma unroll
    for (int r = 0; r < 4; r++) dr[st][r] = __shfl(v, quad*4 + r);
  }
#pragma unroll
  for (int st = 0; st < 2; st++)
#pragma unroll
    for (int i = 0; i < 4; i++)
#pragma unroll
      for (int r = 0; r < 4; r++) {
        int q = q0 + w*32 + st*16 + quad*4 + r;
        O[((size_t)((b*SEQ + q)*NHEAD + h))*DIM_HEAD + i*16 + lid] =
          f2bf(o[st][i][r] * dr[st][r]);
      }
}

extern "C" void kernel_launch(void* const* d_in, const int* in_sizes, int n_in,
                              void* d_out, int out_size, void* d_ws, size_t ws_size,
                              hipStream_t stream) {
  const float* query = (const float*)d_in[0];
  const float* key_  = (const float*)d_in[1];
  const float* value = (const float*)d_in[2];
  const float* Wq = (const float*)d_in[3];
  const float* Wk = (const float*)d_in[4];
  const float* Wv = (const float*)d_in[5];
  const float* Wo = (const float*)d_in[6];
  const float* bo = (const float*)d_in[7];
  float* out = (float*)d_out;

  char* ws = (char*)d_ws;
  // weights: 4x2MB contiguous (z-stride 1<<20 elems)
  unsigned short* WqT = (unsigned short*)(ws + (0ll  << 20));
  unsigned short* WoT = (unsigned short*)(ws + (6ll  << 20));
  unsigned short* Xbf = (unsigned short*)(ws + (8ll  << 20));  // 3x8MB (q,k,v)
  unsigned short* Qb  = (unsigned short*)(ws + (32ll << 20));  // 3x8MB (q,k,v proj)
  unsigned short* Kb  = Qb + MK;
  unsigned short* Vb  = Qb + 2*MK;
  unsigned short* VT  = (unsigned short*)(ws + (8ll  << 20));  // reuse Xbf[q] (dead)
  unsigned short* Ob  = (unsigned short*)(ws + (16ll << 20));  // reuse Xbf[k] (dead)

  dim3 tb(256);
  dim3 tg(32, 32, 4);
  hipLaunchKernelGGL(wtrans_kernel, tg, tb, 0, stream, Wq, Wk, Wv, Wo, WqT);

  dim3 cg(MK / (256*8), 3);        // (2048, 3)
  hipLaunchKernelGGL(cast_kernel, cg, tb, 0, stream, query, key_, value, Xbf);

  dim3 pg(MROWS/128, D_MODEL/128, 3);   // (32, 8, 3) = 768 blocks
  hipLaunchKernelGGL(proj_kernel, pg, tb, 0, stream, Xbf, WqT, Qb);

  dim3 vg(BH, SEQ/64);             // (32, 32)
  hipLaunchKernelGGL(vtrans_kernel, vg, tb, 0, stream, Vb, VT);

  dim3 fg(BH, SEQ/QB);             // (32, 16) = 512 blocks, 2/CU
  hipLaunchKernelGGL(flash_kernel, fg, tb, 0, stream, Qb, Kb, VT, Ob);

  dim3 og(MROWS/64, D_MODEL/128);  // (64, 8) = 512 blocks
  hipLaunchKernelGGL(outproj_kernel, og, tb, 0, stream, Ob, WoT, bo, out);
}

// Round 6
// 210.836 us; speedup vs baseline: 1.1496x; 1.1496x over previous
//
#include <hip/hip_runtime.h>
#include <stdint.h>

typedef __attribute__((ext_vector_type(8))) short short8;
typedef __attribute__((ext_vector_type(8))) unsigned short ushort8;
typedef __attribute__((ext_vector_type(4))) unsigned short ushort4v;
typedef __attribute__((ext_vector_type(4))) float float4v;

#define D_MODEL 1024
#define NHEAD 16
#define DIM_HEAD 64
#define BATCH 2
#define SEQ 2048
#define BH (BATCH*NHEAD)
#define MROWS (BATCH*SEQ)   // 4096
#define MK ((size_t)MROWS * D_MODEL)   // 4194304 elems per activation tensor

__device__ __forceinline__ unsigned short f2bf(float f) {
  union { float f; unsigned u; } v; v.f = f;
  unsigned r = v.u + 0x7fffu + ((v.u >> 16) & 1u);   // RNE
  return (unsigned short)(r >> 16);
}
__device__ __forceinline__ unsigned short f2bf_fast(float f) {
  union { float f; unsigned u; } v; v.f = f;
  return (unsigned short)((v.u + 0x8000u) >> 16);
}

__device__ __forceinline__ float fexp2(float x) {
#if __has_builtin(__builtin_amdgcn_exp2f)
  return __builtin_amdgcn_exp2f(x);
#else
  return exp2f(x);
#endif
}

// async global->LDS, 16B per lane; lds base must be wave-uniform
__device__ __forceinline__ void gld16(const unsigned short* g, unsigned short* l) {
  __builtin_amdgcn_global_load_lds(
      (const __attribute__((address_space(1))) unsigned int*)g,
      (__attribute__((address_space(3))) unsigned int*)l, 16, 0, 0);
}

// ---- weight transpose+cast (all 4 weights in one launch, z picks) ----------
// WT[z][n][k] = bf16(W[z][k][n] * scale[z])
// Wq scale folds SCALE * log2(e) so flash softmax uses exp2 directly.
__global__ __launch_bounds__(256) void wtrans_kernel(const float* __restrict__ W0,
    const float* __restrict__ W1, const float* __restrict__ W2,
    const float* __restrict__ W3, unsigned short* __restrict__ WT) {
  __shared__ float tile[32][33];
  const int z = blockIdx.z;
  const float* W = (z == 0) ? W0 : (z == 1) ? W1 : (z == 2) ? W2 : W3;
  const float scale = (z == 0) ? 0.18033688f : 1.0f;   // 0.125 * log2(e)
  unsigned short* dst = WT + ((size_t)z << 20);
  int bn = blockIdx.x * 32;
  int bk = blockIdx.y * 32;
  int tx = threadIdx.x & 31, ty = threadIdx.x >> 5;
#pragma unroll
  for (int i = 0; i < 4; i++)
    tile[ty + i*8][tx] = W[(size_t)(bk + ty + i*8) * D_MODEL + bn + tx];
  __syncthreads();
#pragma unroll
  for (int i = 0; i < 4; i++)
    dst[(size_t)(bn + ty + i*8) * D_MODEL + bk + tx] = f2bf(tile[tx][ty + i*8] * scale);
}

// ---- cast q/k/v fp32 -> bf16, z picks tensor -------------------------------
__global__ __launch_bounds__(256) void cast_kernel(const float* __restrict__ q,
    const float* __restrict__ k, const float* __restrict__ v,
    unsigned short* __restrict__ out) {
  const float* src = (blockIdx.y == 0) ? q : (blockIdx.y == 1) ? k : v;
  unsigned short* dst = out + (size_t)blockIdx.y * MK;
  size_t idx = ((size_t)blockIdx.x * 256 + threadIdx.x) * 8;
  float4v a = *(const float4v*)(src + idx);
  float4v b = *(const float4v*)(src + idx + 4);
  ushort8 o;
  o[0] = f2bf(a[0]); o[1] = f2bf(a[1]); o[2] = f2bf(a[2]); o[3] = f2bf(a[3]);
  o[4] = f2bf(b[0]); o[5] = f2bf(b[1]); o[6] = f2bf(b[2]); o[7] = f2bf(b[3]);
  *(ushort8*)(dst + idx) = o;
}

// ---- V transpose: Vb [b,n,h,d] -> VT_perm [b,h,d, blk*64 + e] --------------
// Bit-swap perm within each 64-block: row e holds original k(e) =
// 32*(e>>5) + 16*((e>>2)&1) + 4*((e>>3)&3) + (e&3).
// This matches the in-lane layout of exp(S^T) from the swapped QK^T so P
// feeds PV's A-operand directly with ZERO LDS traffic (PV contracts over e).
__global__ __launch_bounds__(256) void vtrans_kernel(const unsigned short* __restrict__ Vb,
                                                     unsigned short* __restrict__ VT) {
  __shared__ unsigned short tile[64][72];
  const int bh = blockIdx.x;
  const int b = bh >> 4, h = bh & 15;
  const int n0 = blockIdx.y * 64;
  const int t = threadIdx.x;
#pragma unroll
  for (int p = 0; p < 2; p++) {
    int g = p*256 + t; int row = g >> 3, c = g & 7;
    *(ushort8*)&tile[row][c*8] =
      *(const ushort8*)(Vb + ((size_t)((b*SEQ + n0 + row)*NHEAD + h))*DIM_HEAD + c*8);
  }
  __syncthreads();
  int d = t >> 2, base = (t & 3) * 16;
  ushort8 o0, o1;
#pragma unroll
  for (int m = 0; m < 8; m++) {
    int e0 = base + m, e1 = base + 8 + m;
    int k0_ = 32*(e0>>5) + 16*((e0>>2)&1) + 4*((e0>>3)&3) + (e0&3);
    int k1_ = 32*(e1>>5) + 16*((e1>>2)&1) + 4*((e1>>3)&3) + (e1&3);
    o0[m] = tile[k0_][d];
    o1[m] = tile[k1_][d];
  }
  unsigned short* dst = VT + ((size_t)(bh*DIM_HEAD + d))*SEQ + n0 + base;
  *(ushort8*)dst = o0;
  *(ushort8*)(dst + 8) = o1;
}

// ---- fused QKV projection: z in {0,1,2}; m97-style (unpadded LDS + gld16) --
// Y[z](bf16)[4096,1024] = Xbf[z] @ W[z],  WT[z] is B^T [N,K]
__global__ __launch_bounds__(256, 3) void proj_kernel(const unsigned short* __restrict__ Xbf,
    const unsigned short* __restrict__ WT0, unsigned short* __restrict__ Y0) {
  __shared__ unsigned short Al[128*64];   // 16 KB, row stride 64 (unpadded)
  __shared__ unsigned short Bl[128*64];   // 16 KB
  const int z = blockIdx.z;
  const unsigned short* A  = Xbf + (size_t)z * MK;
  const unsigned short* BT = WT0 + ((size_t)z << 20);
  unsigned short* Y = Y0 + (size_t)z * MK;
  const int m0 = blockIdx.x * 128, n0 = blockIdx.y * 128;
  const int t = threadIdx.x;
  const int lane = t & 63, w = t >> 6, quad = lane >> 4, lid = lane & 15;
  const int wm = w & 1, wn = w >> 1;
  const int r8 = lane >> 3, c8 = (lane & 7) * 8;

  float4v acc[4][4];
#pragma unroll
  for (int i = 0; i < 4; i++)
#pragma unroll
    for (int j = 0; j < 4; j++) acc[i][j] = (float4v)0.0f;

  for (int k0 = 0; k0 < D_MODEL; k0 += 64) {
#pragma unroll
    for (int p = 0; p < 4; p++) {
      int seg = w*4 + p;   // 16 segs x 8 rows x 1KB
      gld16(A  + (size_t)(m0 + seg*8 + r8) * D_MODEL + k0 + c8, &Al[seg*8*64]);
      gld16(BT + (size_t)(n0 + seg*8 + r8) * D_MODEL + k0 + c8, &Bl[seg*8*64]);
    }
    __syncthreads();
#pragma unroll
    for (int kst = 0; kst < 2; kst++) {
      short8 af[4], bfr[4];
#pragma unroll
      for (int i = 0; i < 4; i++)
        af[i] = *(const short8*)&Al[(wm*64 + i*16 + lid)*64 + kst*32 + quad*8];
#pragma unroll
      for (int j = 0; j < 4; j++)
        bfr[j] = *(const short8*)&Bl[(wn*64 + j*16 + lid)*64 + kst*32 + quad*8];
#pragma unroll
      for (int i = 0; i < 4; i++)
#pragma unroll
        for (int j = 0; j < 4; j++)
          acc[i][j] = __builtin_amdgcn_mfma_f32_16x16x32_bf16(af[i], bfr[j], acc[i][j], 0, 0, 0);
    }
    __syncthreads();
  }
#pragma unroll
  for (int i = 0; i < 4; i++)
#pragma unroll
    for (int j = 0; j < 4; j++)
#pragma unroll
      for (int r = 0; r < 4; r++) {
        int row = m0 + wm*64 + i*16 + quad*4 + r;
        int col = n0 + wn*64 + j*16 + lid;
        Y[(size_t)row * D_MODEL + col] = f2bf_fast(acc[i][j][r]);
      }
}

// ---- output projection: out(fp32)[4096,1024] = A(bf16) @ Wo + bo -----------
// BM=64, BN=128 -> 512 blocks (2/CU)
__global__ __launch_bounds__(256, 3) void outproj_kernel(const unsigned short* __restrict__ A,
    const unsigned short* __restrict__ WT, const float* __restrict__ bias,
    float* __restrict__ out) {
  __shared__ unsigned short Al[64*64];    //  8 KB
  __shared__ unsigned short Bl[128*64];   // 16 KB
  const int m0 = blockIdx.x * 64, n0 = blockIdx.y * 128;
  const int t = threadIdx.x;
  const int lane = t & 63, w = t >> 6, quad = lane >> 4, lid = lane & 15;
  const int wm = w & 1, wn = w >> 1;
  const int r8 = lane >> 3, c8 = (lane & 7) * 8;

  float4v acc[2][4];
#pragma unroll
  for (int i = 0; i < 2; i++)
#pragma unroll
    for (int j = 0; j < 4; j++) acc[i][j] = (float4v)0.0f;

  for (int k0 = 0; k0 < D_MODEL; k0 += 64) {
#pragma unroll
    for (int p = 0; p < 2; p++) {
      int seg = w*2 + p;   // 8 segs for A
      gld16(A + (size_t)(m0 + seg*8 + r8) * D_MODEL + k0 + c8, &Al[seg*8*64]);
    }
#pragma unroll
    for (int p = 0; p < 4; p++) {
      int seg = w*4 + p;   // 16 segs for B
      gld16(WT + (size_t)(n0 + seg*8 + r8) * D_MODEL + k0 + c8, &Bl[seg*8*64]);
    }
    __syncthreads();
#pragma unroll
    for (int kst = 0; kst < 2; kst++) {
      short8 af[2], bfr[4];
#pragma unroll
      for (int i = 0; i < 2; i++)
        af[i] = *(const short8*)&Al[(wm*32 + i*16 + lid)*64 + kst*32 + quad*8];
#pragma unroll
      for (int j = 0; j < 4; j++)
        bfr[j] = *(const short8*)&Bl[(wn*64 + j*16 + lid)*64 + kst*32 + quad*8];
#pragma unroll
      for (int i = 0; i < 2; i++)
#pragma unroll
        for (int j = 0; j < 4; j++)
          acc[i][j] = __builtin_amdgcn_mfma_f32_16x16x32_bf16(af[i], bfr[j], acc[i][j], 0, 0, 0);
    }
    __syncthreads();
  }
#pragma unroll
  for (int i = 0; i < 2; i++)
#pragma unroll
    for (int j = 0; j < 4; j++)
#pragma unroll
      for (int r = 0; r < 4; r++) {
        int row = m0 + wm*32 + i*16 + quad*4 + r;
        int col = n0 + wn*64 + j*16 + lid;
        out[(size_t)row * D_MODEL + col] = acc[i][j][r] + bias[col];
      }
}

// ---- flash attention v6: r3 structure (4 waves x 32q, QB=128, 2 blk/CU,
// K+V LDS dbuf, reg prefetch, P in regs) + VALU-chain cuts:
//   * exp2 instead of exp (log2(e) folded into Wq scale) -> no v_mul per elem
//   * v_cvt_pk_bf16_f32 pack (1 instr / 2 elems) replaces f2bf+insert
#define QB 128
#define KB 64
#define FSTR 72
#define NT (SEQ/KB)   // 32

__global__ __launch_bounds__(256, 2) void flash_kernel(const unsigned short* __restrict__ Q,
    const unsigned short* __restrict__ K, const unsigned short* __restrict__ VT,
    unsigned short* __restrict__ O) {
  __shared__ unsigned short Kl[2][KB][FSTR];        // 18 KB
  __shared__ unsigned short Vt[2][DIM_HEAD][FSTR];  // 18 KB

  const int bh = blockIdx.x;
  const int b = bh >> 4, h = bh & 15;
  const int q0 = blockIdx.y * QB;
  const int t = threadIdx.x;
  const int lane = t & 63, w = t >> 6, quad = lane >> 4, lid = lane & 15;
  const int prow = t >> 3, pc = (t & 7) * 8;   // 32 rows x 8 chunks; p adds 32 rows

  const unsigned short* Kbase = K + ((size_t)(b*SEQ)*NHEAD + h)*DIM_HEAD;
  const unsigned short* Vbase = VT + (size_t)bh*DIM_HEAD*SEQ;

  // Q direct to regs: wave w owns q-rows q0 + w*32 .. +31 (2 st tiles of 16)
  short8 qf[2][2];
#pragma unroll
  for (int st = 0; st < 2; st++)
#pragma unroll
    for (int kst = 0; kst < 2; kst++)
      qf[st][kst] = *(const short8*)(Q +
          ((size_t)((b*SEQ + q0 + w*32 + st*16 + lid)*NHEAD + h))*DIM_HEAD + kst*32 + quad*8);

  float4v o[2][4];
#pragma unroll
  for (int st = 0; st < 2; st++)
#pragma unroll
    for (int i = 0; i < 4; i++) o[st][i] = (float4v)0.0f;
  float ps[2] = {0.0f, 0.0f};

  auto LOADT = [&](int kb, ushort8* kr, ushort8* vr) {
#pragma unroll
    for (int p = 0; p < 2; p++) {
      int row = p*32 + prow;
      kr[p] = *(const ushort8*)(Kbase + (size_t)(kb + row) * D_MODEL + pc);
      vr[p] = *(const ushort8*)(Vbase + (size_t)row * SEQ + kb + pc);
    }
  };
  auto COMMIT = [&](int bi, const ushort8* kr, const ushort8* vr) {
#pragma unroll
    for (int p = 0; p < 2; p++) {
      int row = p*32 + prow;
      *(ushort8*)&Kl[bi][row][pc] = kr[p];
      *(ushort8*)&Vt[bi][row][pc] = vr[p];
    }
  };
  auto STEP = [&](int bi) {
    float4v s[2][4];
#pragma unroll
    for (int st = 0; st < 2; st++)
#pragma unroll
      for (int n = 0; n < 4; n++) s[st][n] = (float4v)0.0f;
    __builtin_amdgcn_s_setprio(1);
#pragma unroll
    for (int kst = 0; kst < 2; kst++)
#pragma unroll
      for (int n = 0; n < 4; n++) {
        short8 kf = *(const short8*)&Kl[bi][n*16 + lid][kst*32 + quad*8];
        s[0][n] = __builtin_amdgcn_mfma_f32_16x16x32_bf16(kf, qf[0][kst], s[0][n], 0, 0, 0);
        s[1][n] = __builtin_amdgcn_mfma_f32_16x16x32_bf16(kf, qf[1][kst], s[1][n], 0, 0, 0);
      }
    __builtin_amdgcn_s_setprio(0);
    // lane (quad,lid) holds S[q = st*16+lid][k = n*16 + quad*4 + r] (x log2e).
    // p = exp2(s); pack pairs via v_cvt_pk_bf16_f32 into PV A-frag slot
    // j = 4*(n&1)+r of half n>>1 (k-order matches VT's bit-swap perm).
    union PF { unsigned u[4]; short8 v8; };
    PF pf0[2], pf1[2];
#pragma unroll
    for (int n = 0; n < 4; n++) {
      float p0[4], p1[4];
#pragma unroll
      for (int r = 0; r < 4; r++) {
        p0[r] = fexp2(s[0][n][r]);
        p1[r] = fexp2(s[1][n][r]);
        ps[0] += p0[r]; ps[1] += p1[r];
      }
      const int hh = n >> 1, bb = 2*(n & 1);
      asm("v_cvt_pk_bf16_f32 %0, %1, %2" : "=v"(pf0[hh].u[bb+0]) : "v"(p0[0]), "v"(p0[1]));
      asm("v_cvt_pk_bf16_f32 %0, %1, %2" : "=v"(pf0[hh].u[bb+1]) : "v"(p0[2]), "v"(p0[3]));
      asm("v_cvt_pk_bf16_f32 %0, %1, %2" : "=v"(pf1[hh].u[bb+0]) : "v"(p1[0]), "v"(p1[1]));
      asm("v_cvt_pk_bf16_f32 %0, %1, %2" : "=v"(pf1[hh].u[bb+1]) : "v"(p1[2]), "v"(p1[3]));
    }
    __builtin_amdgcn_s_setprio(1);
#pragma unroll
    for (int kst = 0; kst < 2; kst++)
#pragma unroll
      for (int i = 0; i < 4; i++) {
        short8 vf = *(const short8*)&Vt[bi][i*16 + lid][kst*32 + quad*8];
        o[0][i] = __builtin_amdgcn_mfma_f32_16x16x32_bf16(pf0[kst].v8, vf, o[0][i], 0, 0, 0);
        o[1][i] = __builtin_amdgcn_mfma_f32_16x16x32_bf16(pf1[kst].v8, vf, o[1][i], 0, 0, 0);
      }
    __builtin_amdgcn_s_setprio(0);
  };

  // depth-2 register pipeline: regsA/regsB alternate tiles
  ushort8 krA[2], vrA[2], krB[2], vrB[2];
  LOADT(0, krA, vrA);
  LOADT(KB, krB, vrB);
  COMMIT(0, krA, vrA);
  __syncthreads();

  for (int i = 0; i < NT; i += 2) {
    // iter i: compute buf0; regsB holds tile i+1; refill regsA with tile i+2
    if (i + 2 < NT) LOADT((i + 2)*KB, krA, vrA);
    STEP(0);
    if (i + 1 < NT) COMMIT(1, krB, vrB);
    __syncthreads();
    // iter i+1: compute buf1; regsA holds tile i+2; refill regsB with tile i+3
    if (i + 3 < NT) LOADT((i + 3)*KB, krB, vrB);
    STEP(1);
    if (i + 2 < NT) COMMIT(0, krA, vrA);
    __syncthreads();
  }

  // softmax denominators: lane holds partial sum for q = st*16+lid (its quad's
  // k-slice); reduce across quads, then fetch denom for output rows quad*4+r.
  float dr[2][4];
#pragma unroll
  for (int st = 0; st < 2; st++) {
    float v = ps[st];
    v += __shfl_xor(v, 16);
    v += __shfl_xor(v, 32);
    v = 1.0f / v;
#pragma unroll
    for (int r = 0; r < 4; r++) dr[st][r] = __shfl(v, quad*4 + r);
  }
#pragma unroll
  for (int st = 0; st < 2; st++)
#pragma unroll
    for (int i = 0; i < 4; i++)
#pragma unroll
      for (int r = 0; r < 4; r++) {
        int q = q0 + w*32 + st*16 + quad*4 + r;
        O[((size_t)((b*SEQ + q)*NHEAD + h))*DIM_HEAD + i*16 + lid] =
          f2bf(o[st][i][r] * dr[st][r]);
      }
}

extern "C" void kernel_launch(void* const* d_in, const int* in_sizes, int n_in,
                              void* d_out, int out_size, void* d_ws, size_t ws_size,
                              hipStream_t stream) {
  const float* query = (const float*)d_in[0];
  const float* key_  = (const float*)d_in[1];
  const float* value = (const float*)d_in[2];
  const float* Wq = (const float*)d_in[3];
  const float* Wk = (const float*)d_in[4];
  const float* Wv = (const float*)d_in[5];
  const float* Wo = (const float*)d_in[6];
  const float* bo = (const float*)d_in[7];
  float* out = (float*)d_out;

  char* ws = (char*)d_ws;
  // weights: 4x2MB contiguous (z-stride 1<<20 elems)
  unsigned short* WqT = (unsigned short*)(ws + (0ll  << 20));
  unsigned short* WoT = (unsigned short*)(ws + (6ll  << 20));
  unsigned short* Xbf = (unsigned short*)(ws + (8ll  << 20));  // 3x8MB (q,k,v)
  unsigned short* Qb  = (unsigned short*)(ws + (32ll << 20));  // 3x8MB (q,k,v proj)
  unsigned short* Kb  = Qb + MK;
  unsigned short* Vb  = Qb + 2*MK;
  unsigned short* VT  = (unsigned short*)(ws + (8ll  << 20));  // reuse Xbf[q] (dead)
  unsigned short* Ob  = (unsigned short*)(ws + (16ll << 20));  // reuse Xbf[k] (dead)

  dim3 tb(256);
  dim3 tg(32, 32, 4);
  hipLaunchKernelGGL(wtrans_kernel, tg, tb, 0, stream, Wq, Wk, Wv, Wo, WqT);

  dim3 cg(MK / (256*8), 3);        // (2048, 3)
  hipLaunchKernelGGL(cast_kernel, cg, tb, 0, stream, query, key_, value, Xbf);

  dim3 pg(MROWS/128, D_MODEL/128, 3);   // (32, 8, 3) = 768 blocks
  hipLaunchKernelGGL(proj_kernel, pg, tb, 0, stream, Xbf, WqT, Qb);

  dim3 vg(BH, SEQ/64);             // (32, 32)
  hipLaunchKernelGGL(vtrans_kernel, vg, tb, 0, stream, Vb, VT);

  dim3 fg(BH, SEQ/QB);             // (32, 16) = 512 blocks, 2/CU
  hipLaunchKernelGGL(flash_kernel, fg, tb, 0, stream, Qb, Kb, VT, Ob);

  dim3 og(MROWS/64, D_MODEL/128);  // (64, 8) = 512 blocks
  hipLaunchKernelGGL(outproj_kernel, og, tb, 0, stream, Ob, WoT, bo, out);
}

// Round 8
// 205.116 us; speedup vs baseline: 1.1817x; 1.0279x over previous
//
#include <hip/hip_runtime.h>
#include <stdint.h>

typedef __attribute__((ext_vector_type(8))) short short8;
typedef __attribute__((ext_vector_type(8))) unsigned short ushort8;
typedef __attribute__((ext_vector_type(4))) unsigned short ushort4v;
typedef __attribute__((ext_vector_type(4))) float float4v;

#define D_MODEL 1024
#define NHEAD 16
#define DIM_HEAD 64
#define BATCH 2
#define SEQ 2048
#define BH (BATCH*NHEAD)
#define MROWS (BATCH*SEQ)   // 4096
#define MK ((size_t)MROWS * D_MODEL)   // 4194304 elems per activation tensor

__device__ __forceinline__ unsigned short f2bf(float f) {
  union { float f; unsigned u; } v; v.f = f;
  unsigned r = v.u + 0x7fffu + ((v.u >> 16) & 1u);   // RNE
  return (unsigned short)(r >> 16);
}
__device__ __forceinline__ unsigned short f2bf_fast(float f) {
  union { float f; unsigned u; } v; v.f = f;
  return (unsigned short)((v.u + 0x8000u) >> 16);
}

__device__ __forceinline__ float fexp2(float x) {
#if __has_builtin(__builtin_amdgcn_exp2f)
  return __builtin_amdgcn_exp2f(x);
#else
  return exp2f(x);
#endif
}

// async global->LDS, 16B per lane; lds base must be wave-uniform
__device__ __forceinline__ void gld16(const unsigned short* g, unsigned short* l) {
  __builtin_amdgcn_global_load_lds(
      (const __attribute__((address_space(1))) unsigned int*)g,
      (__attribute__((address_space(3))) unsigned int*)l, 16, 0, 0);
}

// ---- prep: cast q/k/v fp32->bf16 (y<3) + weight transpose+cast (y==3) ------
// WT[z][n][k] = bf16(W[z][k][n] * scale[z]); Wq scale folds SCALE*log2(e).
__global__ __launch_bounds__(256) void prep_kernel(const float* __restrict__ q,
    const float* __restrict__ k, const float* __restrict__ v,
    unsigned short* __restrict__ Xbf,
    const float* __restrict__ W0, const float* __restrict__ W1,
    const float* __restrict__ W2, const float* __restrict__ W3,
    unsigned short* __restrict__ WT) {
  if (blockIdx.y < 3) {
    const float* src = (blockIdx.y == 0) ? q : (blockIdx.y == 1) ? k : v;
    unsigned short* dst = Xbf + (size_t)blockIdx.y * MK;
    size_t idx = ((size_t)blockIdx.x * 256 + threadIdx.x) * 8;
    float4v a = *(const float4v*)(src + idx);
    float4v b = *(const float4v*)(src + idx + 4);
    ushort8 o;
    o[0] = f2bf(a[0]); o[1] = f2bf(a[1]); o[2] = f2bf(a[2]); o[3] = f2bf(a[3]);
    o[4] = f2bf(b[0]); o[5] = f2bf(b[1]); o[6] = f2bf(b[2]); o[7] = f2bf(b[3]);
    *(ushort8*)(dst + idx) = o;
    return;
  }
  // wtrans: 2048 blocks x 2 tiles; weight z = x>>9, tiles (x&511)*2 + rep
  __shared__ float tile[32][33];
  const int z = blockIdx.x >> 9;
  const float* W = (z == 0) ? W0 : (z == 1) ? W1 : (z == 2) ? W2 : W3;
  const float scale = (z == 0) ? 0.18033688f : 1.0f;   // 0.125 * log2(e)
  unsigned short* dst = WT + ((size_t)z << 20);
  int tx = threadIdx.x & 31, ty = threadIdx.x >> 5;
#pragma unroll
  for (int rep = 0; rep < 2; rep++) {
    int tl = (blockIdx.x & 511) * 2 + rep;
    int bn = (tl & 31) * 32;
    int bk = (tl >> 5) * 32;
#pragma unroll
    for (int i = 0; i < 4; i++)
      tile[ty + i*8][tx] = W[(size_t)(bk + ty + i*8) * D_MODEL + bn + tx];
    __syncthreads();
#pragma unroll
    for (int i = 0; i < 4; i++)
      dst[(size_t)(bn + ty + i*8) * D_MODEL + bk + tx] = f2bf(tile[tx][ty + i*8] * scale);
    __syncthreads();
  }
}

// ---- fused QKV projection: z in {0,1,2}; m97-style (unpadded LDS + gld16) --
// Y[z](bf16)[4096,1024] = Xbf[z] @ W[z],  WT[z] is B^T [N,K]
// z==2 epilogue writes V DIRECTLY in VT_perm layout [b,h,d, blk*64 + e]:
//   slot e holds original k(e) = 32*e5 + 16*e2 + 4*e[4:3] + e[1:0]
//   inverse: e(n) = (n5<<5)|(n[3:2]<<3)|(n4<<2)|n[1:0]
//   epilogue n_local bits: n5n4 = i, n3n2 = quad, n1n0 = r
//   -> e = ((i>>1)<<5)|(quad<<3)|((i&1)<<2)|r : 4 consecutive slots per (i,j)
//   => one 8B store per (i,j). Matches flash's swapped-QK^T P-fragment order.
__global__ __launch_bounds__(256, 3) void proj_kernel(const unsigned short* __restrict__ Xbf,
    const unsigned short* __restrict__ WT0, unsigned short* __restrict__ Y0) {
  __shared__ unsigned short Al[128*64];   // 16 KB, row stride 64 (unpadded)
  __shared__ unsigned short Bl[128*64];   // 16 KB
  const int z = blockIdx.z;
  const unsigned short* A  = Xbf + (size_t)z * MK;
  const unsigned short* BT = WT0 + ((size_t)z << 20);
  unsigned short* Y = Y0 + (size_t)z * MK;
  const int m0 = blockIdx.x * 128, n0 = blockIdx.y * 128;
  const int t = threadIdx.x;
  const int lane = t & 63, w = t >> 6, quad = lane >> 4, lid = lane & 15;
  const int wm = w & 1, wn = w >> 1;
  const int r8 = lane >> 3, c8 = (lane & 7) * 8;

  float4v acc[4][4];
#pragma unroll
  for (int i = 0; i < 4; i++)
#pragma unroll
    for (int j = 0; j < 4; j++) acc[i][j] = (float4v)0.0f;

  for (int k0 = 0; k0 < D_MODEL; k0 += 64) {
#pragma unroll
    for (int p = 0; p < 4; p++) {
      int seg = w*4 + p;   // 16 segs x 8 rows x 1KB
      gld16(A  + (size_t)(m0 + seg*8 + r8) * D_MODEL + k0 + c8, &Al[seg*8*64]);
      gld16(BT + (size_t)(n0 + seg*8 + r8) * D_MODEL + k0 + c8, &Bl[seg*8*64]);
    }
    __syncthreads();
#pragma unroll
    for (int kst = 0; kst < 2; kst++) {
      short8 af[4], bfr[4];
#pragma unroll
      for (int i = 0; i < 4; i++)
        af[i] = *(const short8*)&Al[(wm*64 + i*16 + lid)*64 + kst*32 + quad*8];
#pragma unroll
      for (int j = 0; j < 4; j++)
        bfr[j] = *(const short8*)&Bl[(wn*64 + j*16 + lid)*64 + kst*32 + quad*8];
#pragma unroll
      for (int i = 0; i < 4; i++)
#pragma unroll
        for (int j = 0; j < 4; j++)
          acc[i][j] = __builtin_amdgcn_mfma_f32_16x16x32_bf16(af[i], bfr[j], acc[i][j], 0, 0, 0);
    }
    __syncthreads();
  }
  if (z == 2) {
    // VT_perm write: Y (the z=2 slot) is interpreted as VT[(b*16+h)*64+d][SEQ]
#pragma unroll
    for (int i = 0; i < 4; i++) {
      int row = m0 + wm*64 + i*16 + quad*4;      // r = 0 base (global seq)
      int b_ = row >> 11;
      int n_ = row & 2047;
      int nblk = n_ & ~63;
      int ebase = ((i >> 1) << 5) | (quad << 3) | ((i & 1) << 2);
#pragma unroll
      for (int j = 0; j < 4; j++) {
        int col = n0 + wn*64 + j*16 + lid;       // h*64 + d
        ushort4v pk;
#pragma unroll
        for (int r = 0; r < 4; r++) pk[r] = f2bf_fast(acc[i][j][r]);
        *(ushort4v*)(Y + ((size_t)((b_*NHEAD + (col >> 6))*DIM_HEAD + (col & 63)))*SEQ
                       + nblk + ebase) = pk;
      }
    }
    return;
  }
#pragma unroll
  for (int i = 0; i < 4; i++)
#pragma unroll
    for (int j = 0; j < 4; j++)
#pragma unroll
      for (int r = 0; r < 4; r++) {
        int row = m0 + wm*64 + i*16 + quad*4 + r;
        int col = n0 + wn*64 + j*16 + lid;
        Y[(size_t)row * D_MODEL + col] = f2bf_fast(acc[i][j][r]);
      }
}

// ---- output projection: out(fp32)[4096,1024] = A(bf16) @ Wo + bo -----------
// BM=64, BN=128 -> 512 blocks (2/CU)
__global__ __launch_bounds__(256, 3) void outproj_kernel(const unsigned short* __restrict__ A,
    const unsigned short* __restrict__ WT, const float* __restrict__ bias,
    float* __restrict__ out) {
  __shared__ unsigned short Al[64*64];    //  8 KB
  __shared__ unsigned short Bl[128*64];   // 16 KB
  const int m0 = blockIdx.x * 64, n0 = blockIdx.y * 128;
  const int t = threadIdx.x;
  const int lane = t & 63, w = t >> 6, quad = lane >> 4, lid = lane & 15;
  const int wm = w & 1, wn = w >> 1;
  const int r8 = lane >> 3, c8 = (lane & 7) * 8;

  float4v acc[2][4];
#pragma unroll
  for (int i = 0; i < 2; i++)
#pragma unroll
    for (int j = 0; j < 4; j++) acc[i][j] = (float4v)0.0f;

  for (int k0 = 0; k0 < D_MODEL; k0 += 64) {
#pragma unroll
    for (int p = 0; p < 2; p++) {
      int seg = w*2 + p;   // 8 segs for A
      gld16(A + (size_t)(m0 + seg*8 + r8) * D_MODEL + k0 + c8, &Al[seg*8*64]);
    }
#pragma unroll
    for (int p = 0; p < 4; p++) {
      int seg = w*4 + p;   // 16 segs for B
      gld16(WT + (size_t)(n0 + seg*8 + r8) * D_MODEL + k0 + c8, &Bl[seg*8*64]);
    }
    __syncthreads();
#pragma unroll
    for (int kst = 0; kst < 2; kst++) {
      short8 af[2], bfr[4];
#pragma unroll
      for (int i = 0; i < 2; i++)
        af[i] = *(const short8*)&Al[(wm*32 + i*16 + lid)*64 + kst*32 + quad*8];
#pragma unroll
      for (int j = 0; j < 4; j++)
        bfr[j] = *(const short8*)&Bl[(wn*64 + j*16 + lid)*64 + kst*32 + quad*8];
#pragma unroll
      for (int i = 0; i < 2; i++)
#pragma unroll
        for (int j = 0; j < 4; j++)
          acc[i][j] = __builtin_amdgcn_mfma_f32_16x16x32_bf16(af[i], bfr[j], acc[i][j], 0, 0, 0);
    }
    __syncthreads();
  }
#pragma unroll
  for (int i = 0; i < 2; i++)
#pragma unroll
    for (int j = 0; j < 4; j++)
#pragma unroll
      for (int r = 0; r < 4; r++) {
        int row = m0 + wm*32 + i*16 + quad*4 + r;
        int col = n0 + wn*64 + j*16 + lid;
        out[(size_t)row * D_MODEL + col] = acc[i][j][r] + bias[col];
      }
}

// ---- flash attention v6: r3 structure (4 waves x 32q, QB=128, 2 blk/CU,
// K+V LDS dbuf, reg prefetch, P in regs) + VALU-chain cuts:
//   * exp2 instead of exp (log2(e) folded into Wq scale) -> no v_mul per elem
//   * v_cvt_pk_bf16_f32 pack (1 instr / 2 elems) replaces f2bf+insert
#define QB 128
#define KB 64
#define FSTR 72
#define NT (SEQ/KB)   // 32

__global__ __launch_bounds__(256, 2) void flash_kernel(const unsigned short* __restrict__ Q,
    const unsigned short* __restrict__ K, const unsigned short* __restrict__ VT,
    unsigned short* __restrict__ O) {
  __shared__ unsigned short Kl[2][KB][FSTR];        // 18 KB
  __shared__ unsigned short Vt[2][DIM_HEAD][FSTR];  // 18 KB

  const int bh = blockIdx.x;
  const int b = bh >> 4, h = bh & 15;
  const int q0 = blockIdx.y * QB;
  const int t = threadIdx.x;
  const int lane = t & 63, w = t >> 6, quad = lane >> 4, lid = lane & 15;
  const int prow = t >> 3, pc = (t & 7) * 8;   // 32 rows x 8 chunks; p adds 32 rows

  const unsigned short* Kbase = K + ((size_t)(b*SEQ)*NHEAD + h)*DIM_HEAD;
  const unsigned short* Vbase = VT + (size_t)bh*DIM_HEAD*SEQ;

  // Q direct to regs: wave w owns q-rows q0 + w*32 .. +31 (2 st tiles of 16)
  short8 qf[2][2];
#pragma unroll
  for (int st = 0; st < 2; st++)
#pragma unroll
    for (int kst = 0; kst < 2; kst++)
      qf[st][kst] = *(const short8*)(Q +
          ((size_t)((b*SEQ + q0 + w*32 + st*16 + lid)*NHEAD + h))*DIM_HEAD + kst*32 + quad*8);

  float4v o[2][4];
#pragma unroll
  for (int st = 0; st < 2; st++)
#pragma unroll
    for (int i = 0; i < 4; i++) o[st][i] = (float4v)0.0f;
  float ps[2] = {0.0f, 0.0f};

  auto LOADT = [&](int kb, ushort8* kr, ushort8* vr) {
#pragma unroll
    for (int p = 0; p < 2; p++) {
      int row = p*32 + prow;
      kr[p] = *(const ushort8*)(Kbase + (size_t)(kb + row) * D_MODEL + pc);
      vr[p] = *(const ushort8*)(Vbase + (size_t)row * SEQ + kb + pc);
    }
  };
  auto COMMIT = [&](int bi, const ushort8* kr, const ushort8* vr) {
#pragma unroll
    for (int p = 0; p < 2; p++) {
      int row = p*32 + prow;
      *(ushort8*)&Kl[bi][row][pc] = kr[p];
      *(ushort8*)&Vt[bi][row][pc] = vr[p];
    }
  };
  auto STEP = [&](int bi) {
    float4v s[2][4];
#pragma unroll
    for (int st = 0; st < 2; st++)
#pragma unroll
      for (int n = 0; n < 4; n++) s[st][n] = (float4v)0.0f;
    __builtin_amdgcn_s_setprio(1);
#pragma unroll
    for (int kst = 0; kst < 2; kst++)
#pragma unroll
      for (int n = 0; n < 4; n++) {
        short8 kf = *(const short8*)&Kl[bi][n*16 + lid][kst*32 + quad*8];
        s[0][n] = __builtin_amdgcn_mfma_f32_16x16x32_bf16(kf, qf[0][kst], s[0][n], 0, 0, 0);
        s[1][n] = __builtin_amdgcn_mfma_f32_16x16x32_bf16(kf, qf[1][kst], s[1][n], 0, 0, 0);
      }
    __builtin_amdgcn_s_setprio(0);
    // lane (quad,lid) holds S[q = st*16+lid][k = n*16 + quad*4 + r] (x log2e).
    // p = exp2(s); pack pairs via v_cvt_pk_bf16_f32 into PV A-frag slot
    // j = 4*(n&1)+r of half n>>1 (k-order matches VT's bit-swap perm).
    union PF { unsigned u[4]; short8 v8; };
    PF pf0[2], pf1[2];
#pragma unroll
    for (int n = 0; n < 4; n++) {
      float p0[4], p1[4];
#pragma unroll
      for (int r = 0; r < 4; r++) {
        p0[r] = fexp2(s[0][n][r]);
        p1[r] = fexp2(s[1][n][r]);
        ps[0] += p0[r]; ps[1] += p1[r];
      }
      const int hh = n >> 1, bb = 2*(n & 1);
      asm("v_cvt_pk_bf16_f32 %0, %1, %2" : "=v"(pf0[hh].u[bb+0]) : "v"(p0[0]), "v"(p0[1]));
      asm("v_cvt_pk_bf16_f32 %0, %1, %2" : "=v"(pf0[hh].u[bb+1]) : "v"(p0[2]), "v"(p0[3]));
      asm("v_cvt_pk_bf16_f32 %0, %1, %2" : "=v"(pf1[hh].u[bb+0]) : "v"(p1[0]), "v"(p1[1]));
      asm("v_cvt_pk_bf16_f32 %0, %1, %2" : "=v"(pf1[hh].u[bb+1]) : "v"(p1[2]), "v"(p1[3]));
    }
    __builtin_amdgcn_s_setprio(1);
#pragma unroll
    for (int kst = 0; kst < 2; kst++)
#pragma unroll
      for (int i = 0; i < 4; i++) {
        short8 vf = *(const short8*)&Vt[bi][i*16 + lid][kst*32 + quad*8];
        o[0][i] = __builtin_amdgcn_mfma_f32_16x16x32_bf16(pf0[kst].v8, vf, o[0][i], 0, 0, 0);
        o[1][i] = __builtin_amdgcn_mfma_f32_16x16x32_bf16(pf1[kst].v8, vf, o[1][i], 0, 0, 0);
      }
    __builtin_amdgcn_s_setprio(0);
  };

  // depth-2 register pipeline: regsA/regsB alternate tiles
  ushort8 krA[2], vrA[2], krB[2], vrB[2];
  LOADT(0, krA, vrA);
  LOADT(KB, krB, vrB);
  COMMIT(0, krA, vrA);
  __syncthreads();

  for (int i = 0; i < NT; i += 2) {
    // iter i: compute buf0; regsB holds tile i+1; refill regsA with tile i+2
    if (i + 2 < NT) LOADT((i + 2)*KB, krA, vrA);
    STEP(0);
    if (i + 1 < NT) COMMIT(1, krB, vrB);
    __syncthreads();
    // iter i+1: compute buf1; regsA holds tile i+2; refill regsB with tile i+3
    if (i + 3 < NT) LOADT((i + 3)*KB, krB, vrB);
    STEP(1);
    if (i + 2 < NT) COMMIT(0, krA, vrA);
    __syncthreads();
  }

  // softmax denominators: lane holds partial sum for q = st*16+lid (its quad's
  // k-slice); reduce across quads, then fetch denom for output rows quad*4+r.
  float dr[2][4];
#pragma unroll
  for (int st = 0; st < 2; st++) {
    float v = ps[st];
    v += __shfl_xor(v, 16);
    v += __shfl_xor(v, 32);
    v = 1.0f / v;
#pragma unroll
    for (int r = 0; r < 4; r++) dr[st][r] = __shfl(v, quad*4 + r);
  }
#pragma unroll
  for (int st = 0; st < 2; st++)
#pragma unroll
    for (int i = 0; i < 4; i++)
#pragma unroll
      for (int r = 0; r < 4; r++) {
        int q = q0 + w*32 + st*16 + quad*4 + r;
        O[((size_t)((b*SEQ + q)*NHEAD + h))*DIM_HEAD + i*16 + lid] =
          f2bf(o[st][i][r] * dr[st][r]);
      }
}

extern "C" void kernel_launch(void* const* d_in, const int* in_sizes, int n_in,
                              void* d_out, int out_size, void* d_ws, size_t ws_size,
                              hipStream_t stream) {
  const float* query = (const float*)d_in[0];
  const float* key_  = (const float*)d_in[1];
  const float* value = (const float*)d_in[2];
  const float* Wq = (const float*)d_in[3];
  const float* Wk = (const float*)d_in[4];
  const float* Wv = (const float*)d_in[5];
  const float* Wo = (const float*)d_in[6];
  const float* bo = (const float*)d_in[7];
  float* out = (float*)d_out;

  char* ws = (char*)d_ws;
  // weights: 4x2MB contiguous (z-stride 1<<20 elems)
  unsigned short* WqT = (unsigned short*)(ws + (0ll  << 20));
  unsigned short* WoT = (unsigned short*)(ws + (6ll  << 20));
  unsigned short* Xbf = (unsigned short*)(ws + (8ll  << 20));  // 3x8MB (q,k,v)
  unsigned short* Qb  = (unsigned short*)(ws + (32ll << 20));  // 3x8MB (q,k,v proj)
  unsigned short* Kb  = Qb + MK;
  unsigned short* VT  = Qb + 2*MK;   // z=2 slot holds VT_perm layout directly
  unsigned short* Ob  = (unsigned short*)(ws + (16ll << 20));  // reuse Xbf[k] (dead)

  dim3 tb(256);
  dim3 pr(2048, 4);                // y<3: cast; y=3: wtrans (2 tiles/block)
  hipLaunchKernelGGL(prep_kernel, pr, tb, 0, stream,
                     query, key_, value, Xbf, Wq, Wk, Wv, Wo, WqT);

  dim3 pg(MROWS/128, D_MODEL/128, 3);   // (32, 8, 3) = 768 blocks
  hipLaunchKernelGGL(proj_kernel, pg, tb, 0, stream, Xbf, WqT, Qb);

  dim3 fg(BH, SEQ/QB);             // (32, 16) = 512 blocks, 2/CU
  hipLaunchKernelGGL(flash_kernel, fg, tb, 0, stream, Qb, Kb, VT, Ob);

  dim3 og(MROWS/64, D_MODEL/128);  // (64, 8) = 512 blocks
  hipLaunchKernelGGL(outproj_kernel, og, tb, 0, stream, Ob, WoT, bo, out);
}